// Round 1
// 664.665 us; speedup vs baseline: 1.0846x; 1.0846x over previous
//
#include <hip/hip_runtime.h>
#include <stdint.h>

#define B_DIM 4
#define S_DIM 2048
#define D_DIM 2048
#define H_DIM 16
#define M_ROWS (B_DIM * S_DIM)   // 8192
#define CONCAT_LD 4096
#define NCHUNK 32
#define CHLEN (S_DIM / NCHUNK)   // 64

#define BM 128
#define BN 128
#define BK 64

typedef __attribute__((ext_vector_type(8))) __bf16 bf16x8;
typedef __attribute__((ext_vector_type(4))) float f32x4;

__device__ inline unsigned short f2bf(float f) {
  union { float f; unsigned u; } x; x.f = f;
  unsigned r = x.u + 0x7fffu + ((x.u >> 16) & 1u);
  return (unsigned short)(r >> 16);
}
__device__ inline float bf2f(unsigned short s) {
  union { unsigned u; float f; } x; x.u = ((unsigned)s) << 16;
  return x.f;
}

// ---- fused: x fp32 -> bf16 into concat[:,0:2048]  AND  logits = x @ W_att ----
__global__ __launch_bounds__(256) void xconv_logits_kernel(
    const float* __restrict__ x, const float* __restrict__ Watt,
    unsigned short* __restrict__ concat, float* __restrict__ logits) {
  int row = blockIdx.x, t = threadIdx.x;
  const float* xr = x + (size_t)row * D_DIM;
  unsigned short* cr = concat + (size_t)row * CONCAT_LD;
  float p[H_DIM];
#pragma unroll
  for (int h = 0; h < H_DIM; ++h) p[h] = 0.f;
#pragma unroll
  for (int i = 0; i < 8; ++i) {
    int k = t + i * 256;
    float xv = xr[k];
    cr[k] = f2bf(xv);
    const float* wr = Watt + (size_t)k * H_DIM;
#pragma unroll
    for (int h = 0; h < H_DIM; ++h) p[h] += xv * wr[h];
  }
  __shared__ float red[4][H_DIM];
  int l = t & 63, w = t >> 6;
#pragma unroll
  for (int h = 0; h < H_DIM; ++h) {
    float v = p[h];
    for (int off = 32; off; off >>= 1) v += __shfl_down(v, off);
    if (l == 0) red[w][h] = v;
  }
  __syncthreads();
  if (t < H_DIM)
    logits[(size_t)row * H_DIM + t] = red[0][t] + red[1][t] + red[2][t] + red[3][t];
}

// ---- fp32 [R][C] -> bf16 transposed [C][R], dst leading dim ldd ----
__global__ __launch_bounds__(256) void transpose_conv_kernel(
    const float* __restrict__ src, unsigned short* __restrict__ dst,
    int R, int C, int ldd) {
  __shared__ float tile[32][33];
  int c0 = blockIdx.x * 32, r0 = blockIdx.y * 32;
  int tx = threadIdx.x & 31, ty = threadIdx.x >> 5;
#pragma unroll
  for (int i = 0; i < 32; i += 8)
    tile[ty + i][tx] = src[(size_t)(r0 + ty + i) * C + c0 + tx];
  __syncthreads();
#pragma unroll
  for (int i = 0; i < 32; i += 8)
    dst[(size_t)(c0 + ty + i) * ldd + r0 + tx] = f2bf(tile[tx][ty + i]);
}

// ---- fp32 -> bf16 plain convert (contiguous) ----
__global__ __launch_bounds__(256) void convert_kernel(
    const float* __restrict__ src, unsigned short* __restrict__ dst) {
  int idx = (blockIdx.x * 256 + threadIdx.x) * 4;
  const float4 v = *(const float4*)(src + idx);
  ushort4 o;
  o.x = f2bf(v.x); o.y = f2bf(v.y); o.z = f2bf(v.z); o.w = f2bf(v.w);
  *(ushort4*)(dst + idx) = o;
}

// ---- per (b,h): max over s, then coef = w/(w*(s+1)+1e-30), w=exp((lg-mx)*T) ----
__global__ __launch_bounds__(256) void coef_kernel(
    const float* __restrict__ logits, const float* __restrict__ temp, float* __restrict__ coef) {
  int b = blockIdx.x >> 4, h = blockIdx.x & 15;
  int t = threadIdx.x;
  const float* lg = logits + (size_t)b * S_DIM * H_DIM + h;
  float mx = -1e30f;
  for (int s = t; s < S_DIM; s += 256) mx = fmaxf(mx, lg[(size_t)s * H_DIM]);
  for (int off = 32; off; off >>= 1) mx = fmaxf(mx, __shfl_down(mx, off));
  __shared__ float red[4];
  if ((t & 63) == 0) red[t >> 6] = mx;
  __syncthreads();
  mx = fmaxf(fmaxf(red[0], red[1]), fmaxf(red[2], red[3]));
  float T = temp[h];
  float* cf = coef + (size_t)b * S_DIM * H_DIM + h;
  for (int s = t; s < S_DIM; s += 256) {
    float w = expf((lg[(size_t)s * H_DIM] - mx) * T);
    cf[(size_t)s * H_DIM] = w / (w * (float)(s + 1) + 1e-30f);
  }
}

// ---- bias2 = vector @ F1b (+ ff1_b), partial over j-segments then reduce ----
__global__ __launch_bounds__(256) void bias2_partial_kernel(
    const float* __restrict__ vector, const float* __restrict__ ff1,
    float* __restrict__ part) {
  int n = blockIdx.x * 256 + threadIdx.x;
  int seg = blockIdx.y, b = blockIdx.z;
  const float* vr = vector + (size_t)b * 2048 + seg * 128;
  const float* fr = ff1 + (size_t)(2048 + seg * 128) * 2048 + n;
  float acc = 0.f;
#pragma unroll 8
  for (int j = 0; j < 128; ++j) acc += vr[j] * fr[(size_t)j * 2048];
  part[((size_t)seg * 4 + b) * 2048 + n] = acc;
}

__global__ __launch_bounds__(256) void bias2_reduce_kernel(
    const float* __restrict__ part, const float* __restrict__ ff1_b,
    float* __restrict__ bias2) {
  int n = blockIdx.x * 256 + threadIdx.x;
  int b = blockIdx.y;
  float acc = ff1_b[n];
#pragma unroll
  for (int s = 0; s < 16; ++s) acc += part[((size_t)s * 4 + b) * 2048 + n];
  bias2[(size_t)b * 2048 + n] = acc;
}

// ---- 128x128 GEMM (m97 structure) -- kept for the small 2048^3 Wc GEMM ----
template <int MODE>
__global__ __launch_bounds__(256) void gemm_bt_kernel(
    const unsigned short* __restrict__ A, int lda,
    const unsigned short* __restrict__ Bt, int ldb, int K,
    void* __restrict__ outp, int ldo,
    const float* __restrict__ bias, const float* __restrict__ resid) {
  __shared__ unsigned short As[BM * BK];
  __shared__ unsigned short Bs[BN * BK];
  const int t = threadIdx.x;
  const int w = t >> 6, l = t & 63;
  const int wm = w & 1, wn = w >> 1;
  const int q = l >> 4, ln = l & 15;

  const int L = blockIdx.y * 16 + blockIdx.x;
  const int xcd = L & 7;
  const int W = L >> 3;
  const int bx = W & 15;
  const int by = (W >> 4) * 8 + xcd;
  const int m0 = by * BM, n0 = bx * BN;

  f32x4 acc[4][4];
#pragma unroll
  for (int i = 0; i < 4; ++i)
#pragma unroll
    for (int j = 0; j < 4; ++j) acc[i][j] = {0.f, 0.f, 0.f, 0.f};

  for (int k0 = 0; k0 < K; k0 += BK) {
    __syncthreads();
#pragma unroll
    for (int r = 0; r < 4; ++r) {
      int s = r * 256 + t;
      int row = s >> 3;
      int ch = (s & 7) ^ (row & 7);
      const unsigned short* ga = A + (size_t)(m0 + row) * lda + k0 + ch * 8;
      __builtin_amdgcn_global_load_lds(
          (const __attribute__((address_space(1))) void*)ga,
          (__attribute__((address_space(3))) void*)(As + (r * 256 + w * 64) * 8), 16, 0, 0);
      const unsigned short* gb = Bt + (size_t)(n0 + row) * ldb + k0 + ch * 8;
      __builtin_amdgcn_global_load_lds(
          (const __attribute__((address_space(1))) void*)gb,
          (__attribute__((address_space(3))) void*)(Bs + (r * 256 + w * 64) * 8), 16, 0, 0);
    }
    __syncthreads();
#pragma unroll
    for (int h = 0; h < 2; ++h) {
      bf16x8 af[4], bfr[4];
#pragma unroll
      for (int mt = 0; mt < 4; ++mt) {
        int ar = wm * 64 + mt * 16 + ln;
        af[mt] = *(const bf16x8*)&As[ar * BK + (((h * 4 + q) ^ (ar & 7)) * 8)];
      }
#pragma unroll
      for (int nt = 0; nt < 4; ++nt) {
        int br = wn * 64 + nt * 16 + ln;
        bfr[nt] = *(const bf16x8*)&Bs[br * BK + (((h * 4 + q) ^ (br & 7)) * 8)];
      }
#pragma unroll
      for (int mt = 0; mt < 4; ++mt)
#pragma unroll
        for (int nt = 0; nt < 4; ++nt)
          acc[mt][nt] = __builtin_amdgcn_mfma_f32_16x16x32_bf16(af[mt], bfr[nt], acc[mt][nt], 0, 0, 0);
    }
  }

#pragma unroll
  for (int mt = 0; mt < 4; ++mt) {
#pragma unroll
    for (int i = 0; i < 4; ++i) {
      int row = m0 + wm * 64 + mt * 16 + q * 4 + i;
#pragma unroll
      for (int nt = 0; nt < 4; ++nt) {
        int col = n0 + wn * 64 + nt * 16 + ln;
        float vv = acc[mt][nt][i];
        if (MODE == 2) { vv += bias[(size_t)(row >> 11) * 2048 + col]; vv = fmaxf(vv, 0.f); }
        if (MODE == 4) {
          vv += bias[col]; vv = fmaxf(vv, 0.f);
          vv += resid[(size_t)row * 2048 + col];
          ((float*)outp)[(size_t)row * ldo + col] = vv;
        } else {
          ((unsigned short*)outp)[(size_t)row * ldo + col] = f2bf(vv);
        }
      }
    }
  }
}

// ============================================================================
// 256x256 8-phase GEMM (T2+T3+T4+T5 per the m201 template, K-half slot ring).
//   C[M,N] = A[M,K](bf16,lda) * Bt[N,K](bf16,ldb)^T
//   grid = (N/256, M/256), 512 threads (8 waves, 2M x 4N), 128 KiB LDS.
// LDS: As/Bs[buf][khalf][256 rows][32 cols], 64B rows. Swizzle: 16B chunk
//   index ^= (row>>1)&3  -> 2-way bank aliasing on ds_read_b128 (free).
// Schedule per K-tile t (buf c = t&1), 4 phases:
//   p1: read A(kh0) 8x + B(kh0,nt01) 2x | stage A(t+1,kh1)->c^1 | MFMA 16
//   p2: read B(kh0,nt23) 2x            | stage B(t+1,kh1)->c^1 | MFMA 16  vmcnt(8)
//   p3: read A(kh1) 8x + B(kh1,nt01)   | stage A(t+2,kh0)->c   | MFMA 16
//   p4: read B(kh1,nt23)               | stage B(t+2,kh0)->c   | MFMA 16  vmcnt(8)
// Slot overwritten in phase p was last read in phase p-1 (or earlier) and is
// freed by the p-1 closing barrier. vmcnt(8) + in-order VMEM retire proves
// every half-tile landed one full phase before its first ds_read.
// ============================================================================
#define GLD16(g, s)                                                        \
  __builtin_amdgcn_global_load_lds(                                        \
      (const __attribute__((address_space(1))) void*)(g),                  \
      (__attribute__((address_space(3))) void*)(s), 16, 0, 0)
#define BARX() asm volatile("s_barrier" ::: "memory")
#define VMW8() asm volatile("s_waitcnt vmcnt(8)" ::: "memory")
#define VMW0() asm volatile("s_waitcnt vmcnt(0)" ::: "memory")

template <int MODE>
__global__ __launch_bounds__(512, 2) void gemm256_kernel(
    const unsigned short* __restrict__ A, int lda,
    const unsigned short* __restrict__ Bt, int ldb, int K,
    void* __restrict__ outp, int ldo,
    const float* __restrict__ bias, const float* __restrict__ resid) {
  __shared__ unsigned short As[2][2][256 * 32];
  __shared__ unsigned short Bs[2][2][256 * 32];
  const int t = threadIdx.x;
  const int wv = t >> 6, l = t & 63;
  const int wm = wv >> 2, wn = wv & 3;   // 2 x 4 wave grid
  const int q = l >> 4, ln = l & 15;

  // XCD-aware swizzle: 256 blocks -> each XCD owns a contiguous 4x8 band.
  const int L = blockIdx.y * 8 + blockIdx.x;
  const int lin = (L & 7) * 32 + (L >> 3);
  const int m0 = (lin >> 3) * 256, n0 = (lin & 7) * 256;

  // staging coords (identical for both 128-row rounds of a half-tile)
  const int srow = t >> 2;                                    // 0..127
  const int scol = (((t & 3) * 16) ^ (((srow >> 1) & 3) << 4)) >> 1;  // elems
  const unsigned short* Abase = A + (size_t)(m0 + srow) * lda + scol;
  const unsigned short* Bbase = Bt + (size_t)(n0 + srow) * ldb + scol;
  const size_t astep = (size_t)128 * lda, bstep = (size_t)128 * ldb;
  const int axor = ((ln >> 1) & 3) << 3;  // element-domain read swizzle

  f32x4 acc[8][4];
#pragma unroll
  for (int i = 0; i < 8; ++i)
#pragma unroll
    for (int j = 0; j < 4; ++j) acc[i][j] = {0.f, 0.f, 0.f, 0.f};

  auto stageA = [&](int kt, int kh, int buf) {
    const unsigned short* g = Abase + (size_t)kt * 64 + kh * 32;
    GLD16(g, &As[buf][kh][wv * 512]);
    GLD16(g + astep, &As[buf][kh][4096 + wv * 512]);
  };
  auto stageB = [&](int kt, int kh, int buf) {
    const unsigned short* g = Bbase + (size_t)kt * 64 + kh * 32;
    GLD16(g, &Bs[buf][kh][wv * 512]);
    GLD16(g + bstep, &Bs[buf][kh][4096 + wv * 512]);
  };

  bf16x8 a[8], b[2];
  auto loadA = [&](int buf, int h) {
#pragma unroll
    for (int mt = 0; mt < 8; ++mt) {
      int ar = wm * 128 + mt * 16 + ln;
      a[mt] = *(const bf16x8*)&As[buf][h][ar * 32 + ((q * 8) ^ axor)];
    }
  };
  auto loadB2 = [&](int buf, int h, int np) {
#pragma unroll
    for (int i = 0; i < 2; ++i) {
      int br = wn * 64 + (np * 2 + i) * 16 + ln;
      b[i] = *(const bf16x8*)&Bs[buf][h][br * 32 + ((q * 8) ^ axor)];
    }
  };
  auto mm = [&](int np) {
    __builtin_amdgcn_s_setprio(1);
#pragma unroll
    for (int mt = 0; mt < 8; ++mt)
#pragma unroll
      for (int i = 0; i < 2; ++i)
        acc[mt][np * 2 + i] =
            __builtin_amdgcn_mfma_f32_16x16x32_bf16(a[mt], b[i], acc[mt][np * 2 + i], 0, 0, 0);
    __builtin_amdgcn_s_setprio(0);
  };

  const int NT = K >> 6;
  // prologue: tile0 full + tile1 kh0  (6 half-tiles, 12 loads)
  stageA(0, 0, 0); stageB(0, 0, 0);
  stageA(0, 1, 0); stageB(0, 1, 0);
  stageA(1, 0, 1); stageB(1, 0, 1);
  VMW8();   // oldest 4 retired = tile0 kh0 (A+B)
  BARX();

  for (int tt = 0; tt < NT; ++tt) {
    const int c = tt & 1;
    const int t1 = (tt + 1 == NT) ? 0 : tt + 1;          // wrap: harmless re-stage
    const int t2 = (tt + 2 >= NT) ? tt + 2 - NT : tt + 2;
    // ---- phase 1: kh0, nt{0,1} ----
    loadA(c, 0); loadB2(c, 0, 0);
    stageA(t1, 1, c ^ 1);
    BARX();
    mm(0);
    BARX();
    // ---- phase 2: kh0, nt{2,3} ----
    loadB2(c, 0, 1);
    stageB(t1, 1, c ^ 1);
    BARX();
    mm(1);
    VMW8();   // guarantees this tile's kh1 (and older) landed
    BARX();
    // ---- phase 3: kh1, nt{0,1} ----
    loadA(c, 1); loadB2(c, 1, 0);
    stageA(t2, 0, c);
    BARX();
    mm(0);
    BARX();
    // ---- phase 4: kh1, nt{2,3} ----
    loadB2(c, 1, 1);
    stageB(t2, 0, c);
    BARX();
    mm(1);
    VMW8();   // guarantees next tile's kh0 landed
    BARX();
  }
  VMW0();   // drain trailing (wrapped) stages before epilogue / endpgm

#pragma unroll
  for (int mt = 0; mt < 8; ++mt) {
#pragma unroll
    for (int i = 0; i < 4; ++i) {
      int row = m0 + wm * 128 + mt * 16 + q * 4 + i;
#pragma unroll
      for (int nt = 0; nt < 4; ++nt) {
        int col = n0 + wn * 64 + nt * 16 + ln;
        float vv = acc[mt][nt][i];
        if (MODE == 2) { vv += bias[(size_t)(row >> 11) * 2048 + col]; vv = fmaxf(vv, 0.f); }
        if (MODE == 4) {
          vv += bias[col]; vv = fmaxf(vv, 0.f);
          vv += resid[(size_t)row * 2048 + col];
          ((float*)outp)[(size_t)row * ldo + col] = vv;
        } else {
          ((unsigned short*)outp)[(size_t)row * ldo + col] = f2bf(vv);
        }
      }
    }
  }
}

// ---- chunked scan over S of v[b][s][c], fused coef multiply ----
__global__ __launch_bounds__(256) void scan_partial_kernel(
    const unsigned short* __restrict__ v, float* __restrict__ csum) {
  int c = blockIdx.x * 256 + threadIdx.x;
  int chunk = blockIdx.y, b = blockIdx.z;
  const unsigned short* p = v + ((size_t)(b * S_DIM + chunk * CHLEN)) * D_DIM + c;
  float s = 0.f;
#pragma unroll 4
  for (int i = 0; i < CHLEN; ++i) s += bf2f(p[(size_t)i * D_DIM]);
  csum[((size_t)b * NCHUNK + chunk) * D_DIM + c] = s;
}

__global__ __launch_bounds__(256) void scan_offsets_kernel(float* __restrict__ csum) {
  int c = blockIdx.x * 256 + threadIdx.x;
  int b = blockIdx.y;
  float run = 0.f;
  float* p = csum + (size_t)b * NCHUNK * D_DIM + c;
  for (int ch = 0; ch < NCHUNK; ++ch) {
    float tv = p[(size_t)ch * D_DIM];
    p[(size_t)ch * D_DIM] = run;
    run += tv;
  }
}

// writes pooled directly into concat[:, 2048:4096] (ld 4096)
__global__ __launch_bounds__(256) void scan_apply_kernel(
    const unsigned short* __restrict__ v, const float* __restrict__ csum,
    const float* __restrict__ coef, unsigned short* __restrict__ pooled_out) {
  int c = blockIdx.x * 256 + threadIdx.x;
  int chunk = blockIdx.y, b = blockIdx.z;
  int h = c >> 7;
  int row0 = b * S_DIM + chunk * CHLEN;
  float run = csum[((size_t)b * NCHUNK + chunk) * D_DIM + c];
  const unsigned short* vp = v + (size_t)row0 * D_DIM + c;
  unsigned short* po = pooled_out + (size_t)row0 * CONCAT_LD + c;
  const float* cf = coef + (size_t)row0 * H_DIM + h;
#pragma unroll 4
  for (int i = 0; i < CHLEN; ++i) {
    run += bf2f(vp[(size_t)i * D_DIM]);
    po[(size_t)i * CONCAT_LD] = f2bf(cf[(size_t)i * H_DIM] * run);
  }
}

// ---- in-place LayerNorm on d_out rows ----
__global__ __launch_bounds__(256) void ln_kernel(
    float* __restrict__ out, const float* __restrict__ gamma, const float* __restrict__ beta) {
  int row = blockIdx.x, t = threadIdx.x;
  float* pr = out + (size_t)row * D_DIM;
  float vals[8];
  float s = 0.f;
#pragma unroll
  for (int i = 0; i < 8; ++i) { vals[i] = pr[t + i * 256]; s += vals[i]; }
  __shared__ float red[4];
  for (int off = 32; off; off >>= 1) s += __shfl_down(s, off);
  if ((t & 63) == 0) red[t >> 6] = s;
  __syncthreads();
  float mean = (red[0] + red[1] + red[2] + red[3]) * (1.f / D_DIM);
  __syncthreads();
  float c2 = 0.f;
#pragma unroll
  for (int i = 0; i < 8; ++i) { float c = vals[i] - mean; c2 += c * c; }
  for (int off = 32; off; off >>= 1) c2 += __shfl_down(c2, off);
  if ((t & 63) == 0) red[t >> 6] = c2;
  __syncthreads();
  float var = (red[0] + red[1] + red[2] + red[3]) * (1.f / D_DIM);
  float rstd = rsqrtf(var + 1e-6f);
#pragma unroll
  for (int i = 0; i < 8; ++i) {
    int col = t + i * 256;
    pr[col] = (vals[i] - mean) * rstd * gamma[col] + beta[col];
  }
}

extern "C" void kernel_launch(void* const* d_in, const int* in_sizes, int n_in,
                              void* d_out, int out_size, void* d_ws, size_t ws_size,
                              hipStream_t stream) {
  const float* x      = (const float*)d_in[0];
  const float* vector = (const float*)d_in[1];
  const float* W_att  = (const float*)d_in[2];
  const float* temp   = (const float*)d_in[3];
  const float* W_val  = (const float*)d_in[4];
  const float* W_op   = (const float*)d_in[5];
  const float* ff1    = (const float*)d_in[6];
  const float* ff1_b  = (const float*)d_in[7];
  const float* ff2    = (const float*)d_in[8];
  const float* ff2_b  = (const float*)d_in[9];
  const float* gamma  = (const float*)d_in[10];
  const float* beta   = (const float*)d_in[11];
  float* out = (float*)d_out;

  char* ws = (char*)d_ws;
  auto alloc = [&](size_t bytes) {
    char* p = ws; ws += (bytes + 255) & ~(size_t)255; return p;
  };
  unsigned short* concat = (unsigned short*)alloc((size_t)M_ROWS * CONCAT_LD * 2);  // [x | pooled]
  unsigned short* wv_t   = (unsigned short*)alloc((size_t)2048 * 2048 * 2);
  unsigned short* btff1  = (unsigned short*)alloc((size_t)2048 * 4096 * 2);  // [F1a^T | Wc^T] rows n, ld 4096
  unsigned short* f1bT   = (unsigned short*)alloc((size_t)2048 * 2048 * 2);
  unsigned short* wop_bf = (unsigned short*)alloc((size_t)2048 * 2048 * 2);
  unsigned short* ff2_t  = (unsigned short*)alloc((size_t)2048 * 2048 * 2);
  unsigned short* vbuf   = (unsigned short*)alloc((size_t)M_ROWS * 2048 * 2);
  unsigned short* h1     = (unsigned short*)alloc((size_t)M_ROWS * 2048 * 2);
  float* logits = (float*)alloc((size_t)M_ROWS * H_DIM * 4);
  float* coef   = (float*)alloc((size_t)M_ROWS * H_DIM * 4);
  float* csum   = (float*)alloc((size_t)B_DIM * NCHUNK * D_DIM * 4);
  float* part   = (float*)alloc((size_t)16 * 4 * 2048 * 4);
  float* bias2  = (float*)alloc((size_t)4 * 2048 * 4);

  xconv_logits_kernel<<<M_ROWS, 256, 0, stream>>>(x, W_att, concat, logits);
  transpose_conv_kernel<<<dim3(64, 64), 256, 0, stream>>>(W_val, wv_t, 2048, 2048, 2048);
  transpose_conv_kernel<<<dim3(64, 64), 256, 0, stream>>>(ff1, btff1, 2048, 2048, 4096);
  transpose_conv_kernel<<<dim3(64, 64), 256, 0, stream>>>(ff1 + (size_t)2048 * 2048, f1bT, 2048, 2048, 2048);
  convert_kernel<<<2048 * 2048 / 1024, 256, 0, stream>>>(W_op, wop_bf);
  transpose_conv_kernel<<<dim3(64, 64), 256, 0, stream>>>(ff2, ff2_t, 2048, 2048, 2048);
  coef_kernel<<<B_DIM * H_DIM, 256, 0, stream>>>(logits, temp, coef);
  // Wc^T[n][i] = (F1b^T @ W_op^T)[n][i] -> btff1[:, 2048:4096]  (small: keep 128^2)
  gemm_bt_kernel<1><<<dim3(16, 16), 256, 0, stream>>>(
      f1bT, 2048, wop_bf, 2048, 2048, btff1 + 2048, 4096, nullptr, nullptr);
  // bias2 = vector @ F1b + ff1_b
  bias2_partial_kernel<<<dim3(8, 16, 4), 256, 0, stream>>>(vector, ff1, part);
  bias2_reduce_kernel<<<dim3(8, 4), 256, 0, stream>>>(part, ff1_b, bias2);
  // v = x @ W_values   (256^2 8-phase)
  gemm256_kernel<1><<<dim3(8, 32), 512, 0, stream>>>(
      concat, CONCAT_LD, wv_t, 2048, 2048, vbuf, 2048, nullptr, nullptr);
  scan_partial_kernel<<<dim3(8, NCHUNK, B_DIM), 256, 0, stream>>>(vbuf, csum);
  scan_offsets_kernel<<<dim3(8, B_DIM), 256, 0, stream>>>(csum);
  scan_apply_kernel<<<dim3(8, NCHUNK, B_DIM), 256, 0, stream>>>(vbuf, csum, coef, concat + 2048);
  // h1 = relu([x|pooled] @ [F1a;Wc] + bias2[b])   (256^2 8-phase, K=4096)
  gemm256_kernel<2><<<dim3(8, 32), 512, 0, stream>>>(
      concat, CONCAT_LD, btff1, 4096, 4096, h1, 2048, bias2, nullptr);
  // out = relu(h1 @ ff2 + ff2_b) + x   (256^2 8-phase)
  gemm256_kernel<4><<<dim3(8, 32), 512, 0, stream>>>(
      h1, 2048, ff2_t, 2048, 2048, out, 2048, ff2_b, x);
  ln_kernel<<<M_ROWS, 256, 0, stream>>>(out, gamma, beta);
}